// Round 1
// baseline (1679.894 us; speedup 1.0000x reference)
//
#include <hip/hip_runtime.h>
#include <hip/hip_bf16.h>
#include <math.h>

// Problem constants (fixed by the reference: H=2048, V=32000, B=8, T=256, G=4).
#define H_DIM 2048
#define V_DIM 32000
#define BT    2048            // B*T rows
#define TM    128
#define TN    128
#define TK    32
#define NBLK  (V_DIM / TN)    // 250 N-tiles
#define BETA  0.1f
#define EPSR  1e-4f

typedef __attribute__((ext_vector_type(8))) short bf16x8;   // 8 bf16 = 4 VGPRs (guide §3)
typedef __attribute__((ext_vector_type(4))) float f32x4;

// Pack two fp32 -> bf16x2 with round-half (add 0x8000 to mantissa, take high 16).
// 3 VALU ops per 2 elements (2 adds + 1 v_perm). Inputs are finite, |x| < ~30.
__device__ __forceinline__ unsigned pack_bf16x2(float a, float b) {
    unsigned ua = __float_as_uint(a) + 0x8000u;
    unsigned ub = __float_as_uint(b) + 0x8000u;
    // v_perm pool: bytes 0-3 = src1(ua), 4-7 = src0(ub). Select [2,3,6,7]:
    // low ushort = hi16(a), high ushort = hi16(b).
    return __builtin_amdgcn_perm(ub, ua, 0x07060302u);
}

// Online-softmax merge (m,s) <- (m,s) ⊕ (m2,s2). Neutral element: (-3e38, 0).
// (-3e38 not -inf: -inf minus -inf would give NaN through exp.)
__device__ __forceinline__ void merge_ms(float& m, float& s, float m2, float s2) {
    float nm = fmaxf(m, m2);
    s = s * __expf(m - nm) + s2 * __expf(m2 - nm);
    m = nm;
}

// Fused GEMM (C = A[M,K] · Bw[N,K]^T, bf16 MFMA, fp32 inputs converted in staging)
// + per-row online-softmax partials over this block's 128 columns.
// If token != nullptr (ref pass): also gather C[row, token[row]] when that
// column falls in this block (exactly one block/lane per row writes).
__global__ __launch_bounds__(256) void gemm_lse_kernel(
    const float* __restrict__ A,      // BT x H
    const float* __restrict__ Bw,     // V  x H
    float4* __restrict__ part,        // BT x NBLK : {max, sumexp_rel, argmax_col_bits, 0}
    const int* __restrict__ token,    // nullptr on policy pass
    float* __restrict__ gather_out)   // nullptr on policy pass
{
    __shared__ char smem[TM*TK*2 + TN*TK*2];          // 16 KB: sA | sB
    ushort* sA = (ushort*)smem;
    ushort* sB = (ushort*)(smem + TM*TK*2);
    // Epilogue aliases (used only after the K-loop's final barrier):
    float* redM   = (float*)smem;                      // [128][2]
    float* redS   = (float*)(smem + 1024);             // [128][2]
    int*   redC   = (int*)  (smem + 2048);             // [128][2]
    int*   tokloc = (int*)  (smem + 3072);             // [128]

    const int tid  = threadIdx.x;
    const int lane = tid & 63;
    const int wv   = tid >> 6;
    const int wm   = wv >> 1, wn = wv & 1;             // 2x2 wave grid, 64x64 each
    const int q    = lane >> 4, cl = lane & 15;

    const int m0 = blockIdx.x * TM;                    // x fastest: 16 M-blocks share a B-tile in L2
    const int n0 = blockIdx.y * TN;
    const int nb = blockIdx.y;

    // Staging: thread t covers row = t>>1, 16-float segment seg = t&1.
    const int srow = tid >> 1;
    const int sseg = tid & 1;
    const float4* gA = (const float4*)(A  + (size_t)(m0 + srow) * H_DIM) + sseg * 4;
    const float4* gB = (const float4*)(Bw + (size_t)(n0 + srow) * H_DIM) + sseg * 4;
    uint4* wA = (uint4*)sA + srow * 4 + sseg * 2;
    uint4* wB = (uint4*)sB + srow * 4 + sseg * 2;

    f32x4 acc[4][4];
    const f32x4 zero = {0.f, 0.f, 0.f, 0.f};
    #pragma unroll
    for (int i = 0; i < 4; i++)
        #pragma unroll
        for (int j = 0; j < 4; j++) acc[i][j] = zero;

    // Prologue: prefetch K-slice 0 into registers.
    float4 ra0 = gA[0], ra1 = gA[1], ra2 = gA[2], ra3 = gA[3];
    float4 rb0 = gB[0], rb1 = gB[1], rb2 = gB[2], rb3 = gB[3];

    for (int kt = 0; kt < H_DIM; kt += TK) {
        // Convert current slice fp32->bf16, write LDS (2x ds_write_b128 per matrix).
        wA[0] = make_uint4(pack_bf16x2(ra0.x,ra0.y), pack_bf16x2(ra0.z,ra0.w),
                           pack_bf16x2(ra1.x,ra1.y), pack_bf16x2(ra1.z,ra1.w));
        wA[1] = make_uint4(pack_bf16x2(ra2.x,ra2.y), pack_bf16x2(ra2.z,ra2.w),
                           pack_bf16x2(ra3.x,ra3.y), pack_bf16x2(ra3.z,ra3.w));
        wB[0] = make_uint4(pack_bf16x2(rb0.x,rb0.y), pack_bf16x2(rb0.z,rb0.w),
                           pack_bf16x2(rb1.x,rb1.y), pack_bf16x2(rb1.z,rb1.w));
        wB[1] = make_uint4(pack_bf16x2(rb2.x,rb2.y), pack_bf16x2(rb2.z,rb2.w),
                           pack_bf16x2(rb3.x,rb3.y), pack_bf16x2(rb3.z,rb3.w));
        __syncthreads();

        // Prefetch next K-slice; its latency hides under the 16 MFMAs below.
        if (kt + TK < H_DIM) {
            int kq = (kt + TK) >> 2;
            ra0 = gA[kq]; ra1 = gA[kq+1]; ra2 = gA[kq+2]; ra3 = gA[kq+3];
            rb0 = gB[kq]; rb1 = gB[kq+1]; rb2 = gB[kq+2]; rb3 = gB[kq+3];
        }

        bf16x8 af[4], bfr[4];
        #pragma unroll
        for (int i = 0; i < 4; i++) {
            af[i]  = *(const bf16x8*)(sA + (wm*64 + i*16 + cl) * TK + q*8);
            bfr[i] = *(const bf16x8*)(sB + (wn*64 + i*16 + cl) * TK + q*8);
        }
        #pragma unroll
        for (int i = 0; i < 4; i++)
            #pragma unroll
            for (int j = 0; j < 4; j++)
                acc[i][j] = __builtin_amdgcn_mfma_f32_16x16x32_bf16(af[i], bfr[j], acc[i][j], 0, 0, 0);
        __syncthreads();
    }

    // ---- Epilogue: per-row {max, argmax col, sumexp} over this block's 128 cols.
    // C layout (measured, m89): col = lane&15, row = (lane>>4)*4 + reg.
    #pragma unroll
    for (int ti = 0; ti < 4; ti++) {
        #pragma unroll
        for (int r = 0; r < 4; r++) {
            float vals[4];
            #pragma unroll
            for (int j = 0; j < 4; j++) vals[j] = acc[ti][j][r];
            float m = vals[0]; int cj = 0;
            #pragma unroll
            for (int j = 1; j < 4; j++) if (vals[j] > m) { m = vals[j]; cj = j; }
            float s = 0.f;
            #pragma unroll
            for (int j = 0; j < 4; j++) s += __expf(vals[j] - m);
            int cidx = wn*64 + cj*16 + cl;
            // Butterfly over the 16-lane column group (xor 1,2,4,8 stays in group).
            #pragma unroll
            for (int off = 1; off < 16; off <<= 1) {
                float m2 = __shfl_xor(m, off);
                float s2 = __shfl_xor(s, off);
                int   c2 = __shfl_xor(cidx, off);
                float nm = fmaxf(m, m2);
                s = s * __expf(m - nm) + s2 * __expf(m2 - nm);
                if (m2 > m || (m2 == m && c2 < cidx)) cidx = c2;   // first-occurrence ties
                m = nm;
            }
            int rloc = wm*64 + ti*16 + q*4 + r;
            if (cl == 0) { redM[rloc*2+wn] = m; redS[rloc*2+wn] = s; redC[rloc*2+wn] = cidx; }
        }
    }
    __syncthreads();
    if (tid < TM) {
        float ma = redM[tid*2+0], mb = redM[tid*2+1];
        float sa = redS[tid*2+0], sb = redS[tid*2+1];
        int   ca = redC[tid*2+0], cb = redC[tid*2+1];
        float nm = fmaxf(ma, mb);
        float s  = sa * __expf(ma - nm) + sb * __expf(mb - nm);
        int   cc = (mb > ma || (mb == ma && cb < ca)) ? cb : ca;
        part[(size_t)(m0 + tid) * NBLK + nb] = make_float4(nm, s, __int_as_float(n0 + cc), 0.f);
    }

    // ---- Ref pass only: gather C[row, token[row]] if it lives in this block.
    if (token != nullptr) {
        if (tid < TM) tokloc[tid] = token[m0 + tid] - n0;
        __syncthreads();
        #pragma unroll
        for (int ti = 0; ti < 4; ti++) {
            #pragma unroll
            for (int r = 0; r < 4; r++) {
                int rloc = wm*64 + ti*16 + q*4 + r;
                int tl = tokloc[rloc];
                if (tl >= 0 && tl < TN && ((tl >> 6) & 1) == wn && (tl & 15) == cl) {
                    int tjm = (tl >> 4) & 3;
                    float v = acc[ti][0][r];
                    if (tjm == 1) v = acc[ti][1][r];
                    if (tjm == 2) v = acc[ti][2][r];
                    if (tjm == 3) v = acc[ti][3][r];
                    gather_out[m0 + rloc] = v;
                }
            }
        }
    }
}

// Cross-block reduce (policy): merge 250 partials per row -> token, tok_logp.
// tok_logp = max - lse = -log(sum_total) since token IS the argmax.
__global__ __launch_bounds__(256) void reduce_policy_kernel(
    const float4* __restrict__ part, int* __restrict__ token, float* __restrict__ tok_logp)
{
    int row = blockIdx.x, t = threadIdx.x;
    float m = -3.0e38f, s = 0.f; int cc = 0x7fffffff;
    if (t < NBLK) { float4 p = part[(size_t)row * NBLK + t]; m = p.x; s = p.y; cc = __float_as_int(p.z); }
    for (int off = 1; off < 64; off <<= 1) {
        float m2 = __shfl_xor(m, off);
        float s2 = __shfl_xor(s, off);
        int   c2 = __shfl_xor(cc, off);
        float nm = fmaxf(m, m2);
        s = s * __expf(m - nm) + s2 * __expf(m2 - nm);
        if (m2 > m || (m2 == m && c2 < cc)) cc = c2;
        m = nm;
    }
    __shared__ float smM[4], smS[4]; __shared__ int smC[4];
    if ((t & 63) == 0) { smM[t>>6] = m; smS[t>>6] = s; smC[t>>6] = cc; }
    __syncthreads();
    if (t == 0) {
        m = smM[0]; s = smS[0]; cc = smC[0];
        for (int i = 1; i < 4; i++) {
            float m2 = smM[i], s2 = smS[i]; int c2 = smC[i];
            float nm = fmaxf(m, m2);
            s = s * __expf(m - nm) + s2 * __expf(m2 - nm);
            if (m2 > m || (m2 == m && c2 < cc)) cc = c2;
            m = nm;
        }
        token[row] = cc;
        tok_logp[row] = -__logf(s);
    }
}

// Cross-block reduce (ref): lse per row, then k3 KL at the token.
__global__ __launch_bounds__(256) void reduce_ref_kernel(
    const float4* __restrict__ part, const float* __restrict__ tok_logp,
    const float* __restrict__ gathered, float* __restrict__ klrow)
{
    int row = blockIdx.x, t = threadIdx.x;
    float m = -3.0e38f, s = 0.f;
    if (t < NBLK) { float4 p = part[(size_t)row * NBLK + t]; m = p.x; s = p.y; }
    for (int off = 1; off < 64; off <<= 1) {
        float m2 = __shfl_xor(m, off), s2 = __shfl_xor(s, off);
        merge_ms(m, s, m2, s2);
    }
    __shared__ float smM[4], smS[4];
    if ((t & 63) == 0) { smM[t>>6] = m; smS[t>>6] = s; }
    __syncthreads();
    if (t == 0) {
        m = smM[0]; s = smS[0];
        for (int i = 1; i < 4; i++) merge_ms(m, s, smM[i], smS[i]);
        float lse = m + __logf(s);
        float d = (gathered[row] - lse) - tok_logp[row];   // ref_tok_logp - tok_logp
        klrow[row] = __expf(d) - d - 1.0f;
    }
}

// Final: group-relative advantages (groups of 4, ddof=1 std), masked means.
__global__ __launch_bounds__(256) void final_kernel(
    const int* __restrict__ amask, const float* __restrict__ rewards,
    const float* __restrict__ klrow, float* __restrict__ out)
{
    int t = threadIdx.x;                       // 256 threads, 8 rows each, same b per thread
    int b = t >> 5;                            // rows t*8..t*8+7 all in batch b = t/32
    int g = b >> 2;
    float r0 = rewards[g*4+0], r1 = rewards[g*4+1], r2 = rewards[g*4+2], r3 = rewards[g*4+3];
    float mean = 0.25f * (r0 + r1 + r2 + r3);
    float var = ((r0-mean)*(r0-mean) + (r1-mean)*(r1-mean) +
                 (r2-mean)*(r2-mean) + (r3-mean)*(r3-mean)) * (1.0f/3.0f);  // ddof=1
    float adv = (rewards[b] - mean) / (sqrtf(var) + EPSR);

    float ln = 0.f, ms = 0.f, kb = 0.f, mb = 0.f;
    for (int i = 0; i < 8; i++) {
        int row = t*8 + i;
        float mk = (float)amask[row];
        float kl = klrow[row];
        ln += (adv - BETA * kl) * mk;
        ms += mk;
        kb += kl * mk;
        mb += mk;
    }
    __shared__ float sLN[256], sMS[256], sKB[256], sMB[256], sKLb[8];
    sLN[t] = ln; sMS[t] = ms; sKB[t] = kb; sMB[t] = mb;
    __syncthreads();
    if (t < 8) {                               // per-b masked-mean kl over its 32 threads
        float skb = 0.f, smb = 0.f;
        for (int i = 0; i < 32; i++) { skb += sKB[t*32+i]; smb += sMB[t*32+i]; }
        sKLb[t] = skb / smb;
    }
    __syncthreads();
    if (t == 0) {
        float lnt = 0.f, mst = 0.f;
        for (int i = 0; i < 256; i++) { lnt += sLN[i]; mst += sMS[i]; }
        float mkl = 0.f;
        for (int i = 0; i < 8; i++) mkl += sKLb[i];
        out[0] = -lnt / mst;        // loss
        out[1] = mkl * 0.125f;      // mean_kl
    }
}

extern "C" void kernel_launch(void* const* d_in, const int* in_sizes, int n_in,
                              void* d_out, int out_size, void* d_ws, size_t ws_size,
                              hipStream_t stream)
{
    const float* x       = (const float*)d_in[0];
    const float* w       = (const float*)d_in[1];
    const int*   amask   = (const int*)  d_in[2];
    const float* rewards = (const float*)d_in[3];
    const float* rx      = (const float*)d_in[4];
    const float* rw      = (const float*)d_in[5];
    float* out = (float*)d_out;

    // ws layout (~8.22 MB total): partials + per-row arrays.
    char* ws = (char*)d_ws;
    const size_t PART_BYTES = (size_t)BT * NBLK * sizeof(float4);   // 8,192,000
    float4* part     = (float4*)ws;
    int*    token    = (int*)  (ws + PART_BYTES);
    float*  tok_logp = (float*)(ws + PART_BYTES + 8192);
    float*  gathered = (float*)(ws + PART_BYTES + 16384);
    float*  klrow    = (float*)(ws + PART_BYTES + 24576);

    dim3 g(BT / TM, NBLK), blk(256);
    // Policy pass: partials -> token + tok_logp.
    gemm_lse_kernel<<<g, blk, 0, stream>>>(x, w, part, nullptr, nullptr);
    reduce_policy_kernel<<<BT, 256, 0, stream>>>(part, token, tok_logp);
    // Ref pass: partials (reusing buffer) + gathered ref logit at token.
    gemm_lse_kernel<<<g, blk, 0, stream>>>(rx, rw, part, token, gathered);
    reduce_ref_kernel<<<BT, 256, 0, stream>>>(part, tok_logp, gathered, klrow);
    final_kernel<<<1, 256, 0, stream>>>(amask, rewards, klrow, out);
}

// Round 2
// 1362.771 us; speedup vs baseline: 1.2327x; 1.2327x over previous
//
#include <hip/hip_runtime.h>
#include <hip/hip_bf16.h>
#include <math.h>

// Problem constants (fixed by the reference: H=2048, V=32000, B=8, T=256, G=4).
#define H_DIM 2048
#define V_DIM 32000
#define BT    2048            // B*T rows
#define TM    128
#define TN    128
#define TK    32
#define NKT   (H_DIM / TK)    // 64 K-tiles
#define NBLK  (V_DIM / TN)    // 250 N-tiles
#define BETA  0.1f
#define EPSR  1e-4f

typedef __attribute__((ext_vector_type(8))) short bf16x8;   // 8 bf16 = 4 VGPRs
typedef __attribute__((ext_vector_type(4))) float f32x4;

// ---------------- helpers ----------------

// Pack two fp32 -> bf16x2 (round-half-up via +0x8000, take high 16 bits each).
__device__ __forceinline__ unsigned pack_bf16x2(float a, float b) {
    unsigned ua = __float_as_uint(a) + 0x8000u;
    unsigned ub = __float_as_uint(b) + 0x8000u;
    return __builtin_amdgcn_perm(ub, ua, 0x07060302u);
}

__device__ __forceinline__ void merge_ms(float& m, float& s, float m2, float s2) {
    float nm = fmaxf(m, m2);
    s = s * __expf(m - nm) + s2 * __expf(m2 - nm);
    m = nm;
}

// Async global->LDS, 16 B per lane. Per guide §5: LDS dest = wave-uniform base +
// lane*16; we pass lane-linear pointers so either interpretation is identical.
__device__ __forceinline__ void gl_lds16(const void* g, void* l) {
    __builtin_amdgcn_global_load_lds(
        (const __attribute__((address_space(1))) void*)g,
        (__attribute__((address_space(3))) void*)l, 16, 0, 0);
}

// ---------------- pack: fp32 [R,2048] -> bf16 slabs [R/128][64][4][128] x 16B ----------------
// Slab (rt,kt) is 8 KB contiguous: chunk index (kq*128+row) holds
// src[rt*128+row][kt*32+kq*8 .. +8] as 8 bf16. This is exactly the MFMA
// A/B-operand order (lane(q,cl) wants row=cl, k=q*8..q*8+7), so the GEMM's
// ds_read_b128s are lane-contiguous (2-way bank aliasing only = free, m136).
__global__ __launch_bounds__(256) void pack_kernel(
    const float* __restrict__ src, uint4* __restrict__ dst)
{
    __shared__ float tile[128 * 40];       // stride 40 floats: 16B-aligned rows, spread banks
    const int t  = threadIdx.x;
    const int rt = blockIdx.x, kt = blockIdx.y;

    // Coalesced read: 128 rows x 32 floats (128B contiguous per row).
    #pragma unroll
    for (int it = 0; it < 4; it++) {
        int idx = (it * 256 + t) * 4;                  // 0..4095
        int row = idx >> 5, k = idx & 31;
        float4 v = *(const float4*)(src + (size_t)(rt * 128 + row) * H_DIM + kt * 32 + k);
        *(float4*)(tile + row * 40 + k) = v;
    }
    __syncthreads();

    // Coalesced write: 512 x 16B chunks, thread t -> chunks t, t+256.
    uint4* d = dst + ((size_t)(rt * 64 + kt) << 9);
    #pragma unroll
    for (int it = 0; it < 2; it++) {
        int c = it * 256 + t;                          // 0..511
        int kq = c >> 7, row = c & 127;
        const float* p = tile + row * 40 + kq * 8;
        d[c] = make_uint4(pack_bf16x2(p[0], p[1]), pack_bf16x2(p[2], p[3]),
                          pack_bf16x2(p[4], p[5]), pack_bf16x2(p[6], p[7]));
    }
}

// ---------------- fast GEMM (m97 structure) + online-softmax epilogue ----------------
// z=0: policy (Ap x Wp -> part). z=1: ref (Rp x RWp -> part2). No gather here.
__global__ __launch_bounds__(256) void gemm_lse_fast(
    const ushort* __restrict__ Ap, const ushort* __restrict__ Wp,
    const ushort* __restrict__ Rp, const ushort* __restrict__ RWp,
    float4* __restrict__ part, float4* __restrict__ part2)
{
    __shared__ char smem[16384];                       // sA (8KB) | sB (8KB)
    float* redM = (float*)smem;                        // epilogue aliases (post-barrier)
    float* redS = (float*)(smem + 1024);
    int*   redC = (int*)  (smem + 2048);

    const int tid  = threadIdx.x;
    const int lane = tid & 63;
    const int wv   = tid >> 6;
    const int wm   = wv >> 1, wn = wv & 1;             // 2x2 wave grid, 64x64 each
    const int q    = lane >> 4, cl = lane & 15;

    const int mb = blockIdx.x, nb = blockIdx.y;
    const ushort* A  = blockIdx.z ? Rp  : Ap;
    const ushort* Bw = blockIdx.z ? RWp : Wp;
    float4* pp = blockIdx.z ? part2 : part;

    // Staging: waves 0,1 load the A slab (8KB), waves 2,3 the B slab.
    // Each wave: 4 x global_load_lds(16B/lane) = 4KB. All wave-uniform control.
    const ushort* gs = (wv < 2 ? A + (size_t)mb * 64 * 4096
                               : Bw + (size_t)nb * 64 * 4096)
                       + (size_t)(wv & 1) * 4 * 512 + lane * 8;
    char* ls = smem + (wv < 2 ? 0 : 8192) + (wv & 1) * 4 * 1024 + lane * 16;

    f32x4 acc[4][4];
    const f32x4 zero = {0.f, 0.f, 0.f, 0.f};
    #pragma unroll
    for (int i = 0; i < 4; i++)
        #pragma unroll
        for (int j = 0; j < 4; j++) acc[i][j] = zero;

    for (int kt = 0; kt < NKT; kt++) {
        #pragma unroll
        for (int c = 0; c < 4; c++) gl_lds16(gs + c * 512, ls + c * 1024);
        gs += 4096;
        __syncthreads();                               // drains vmcnt; LDS tile ready

        bf16x8 af[4], bfr[4];
        #pragma unroll
        for (int i = 0; i < 4; i++) {
            af[i]  = *(const bf16x8*)(smem + (q * 128 + wm * 64 + i * 16 + cl) * 16);
            bfr[i] = *(const bf16x8*)(smem + 8192 + (q * 128 + wn * 64 + i * 16 + cl) * 16);
        }
        #pragma unroll
        for (int i = 0; i < 4; i++)
            #pragma unroll
            for (int j = 0; j < 4; j++)
                acc[i][j] = __builtin_amdgcn_mfma_f32_16x16x32_bf16(af[i], bfr[j], acc[i][j], 0, 0, 0);
        __syncthreads();
    }

    // Epilogue: per-row {max, argmax col, sumexp} over this block's 128 cols.
    // C layout (m89): col = lane&15, row = (lane>>4)*4 + reg.
    #pragma unroll
    for (int ti = 0; ti < 4; ti++) {
        #pragma unroll
        for (int r = 0; r < 4; r++) {
            float vals[4];
            #pragma unroll
            for (int j = 0; j < 4; j++) vals[j] = acc[ti][j][r];
            float m = vals[0]; int cj = 0;
            #pragma unroll
            for (int j = 1; j < 4; j++) if (vals[j] > m) { m = vals[j]; cj = j; }
            float s = 0.f;
            #pragma unroll
            for (int j = 0; j < 4; j++) s += __expf(vals[j] - m);
            int cidx = wn * 64 + cj * 16 + cl;
            #pragma unroll
            for (int off = 1; off < 16; off <<= 1) {
                float m2 = __shfl_xor(m, off);
                float s2 = __shfl_xor(s, off);
                int   c2 = __shfl_xor(cidx, off);
                float nm = fmaxf(m, m2);
                s = s * __expf(m - nm) + s2 * __expf(m2 - nm);
                if (m2 > m || (m2 == m && c2 < cidx)) cidx = c2;   // first-occurrence ties
                m = nm;
            }
            int rloc = wm * 64 + ti * 16 + q * 4 + r;
            if (cl == 0) { redM[rloc*2+wn] = m; redS[rloc*2+wn] = s; redC[rloc*2+wn] = cidx; }
        }
    }
    __syncthreads();
    if (tid < TM) {
        float ma = redM[tid*2+0], mb2 = redM[tid*2+1];
        float sa = redS[tid*2+0], sb  = redS[tid*2+1];
        int   ca = redC[tid*2+0], cb  = redC[tid*2+1];
        float nm = fmaxf(ma, mb2);
        float s  = sa * __expf(ma - nm) + sb * __expf(mb2 - nm);
        int   cc = (mb2 > ma || (mb2 == ma && cb < ca)) ? cb : ca;
        pp[(size_t)(mb * TM + tid) * NBLK + nb] =
            make_float4(nm, s, __int_as_float(nb * TN + cc), 0.f);
    }
}

// ---------------- fallback GEMM (round-1, in-kernel convert + gather) ----------------
__global__ __launch_bounds__(256) void gemm_lse_fallback(
    const float* __restrict__ A, const float* __restrict__ Bw,
    float4* __restrict__ part, const int* __restrict__ token,
    float* __restrict__ gather_out)
{
    __shared__ char smem[TM*TK*2 + TN*TK*2];
    ushort* sA = (ushort*)smem;
    ushort* sB = (ushort*)(smem + TM*TK*2);
    float* redM   = (float*)smem;
    float* redS   = (float*)(smem + 1024);
    int*   redC   = (int*)  (smem + 2048);
    int*   tokloc = (int*)  (smem + 3072);

    const int tid  = threadIdx.x;
    const int lane = tid & 63;
    const int wv   = tid >> 6;
    const int wm   = wv >> 1, wn = wv & 1;
    const int q    = lane >> 4, cl = lane & 15;
    const int m0 = blockIdx.x * TM;
    const int n0 = blockIdx.y * TN;
    const int nb = blockIdx.y;

    const int srow = tid >> 1, sseg = tid & 1;
    const float4* gA = (const float4*)(A  + (size_t)(m0 + srow) * H_DIM) + sseg * 4;
    const float4* gB = (const float4*)(Bw + (size_t)(n0 + srow) * H_DIM) + sseg * 4;
    uint4* wA = (uint4*)sA + srow * 4 + sseg * 2;
    uint4* wB = (uint4*)sB + srow * 4 + sseg * 2;

    f32x4 acc[4][4];
    const f32x4 zero = {0.f, 0.f, 0.f, 0.f};
    #pragma unroll
    for (int i = 0; i < 4; i++)
        #pragma unroll
        for (int j = 0; j < 4; j++) acc[i][j] = zero;

    float4 ra0 = gA[0], ra1 = gA[1], ra2 = gA[2], ra3 = gA[3];
    float4 rb0 = gB[0], rb1 = gB[1], rb2 = gB[2], rb3 = gB[3];

    for (int kt = 0; kt < H_DIM; kt += TK) {
        wA[0] = make_uint4(pack_bf16x2(ra0.x,ra0.y), pack_bf16x2(ra0.z,ra0.w),
                           pack_bf16x2(ra1.x,ra1.y), pack_bf16x2(ra1.z,ra1.w));
        wA[1] = make_uint4(pack_bf16x2(ra2.x,ra2.y), pack_bf16x2(ra2.z,ra2.w),
                           pack_bf16x2(ra3.x,ra3.y), pack_bf16x2(ra3.z,ra3.w));
        wB[0] = make_uint4(pack_bf16x2(rb0.x,rb0.y), pack_bf16x2(rb0.z,rb0.w),
                           pack_bf16x2(rb1.x,rb1.y), pack_bf16x2(rb1.z,rb1.w));
        wB[1] = make_uint4(pack_bf16x2(rb2.x,rb2.y), pack_bf16x2(rb2.z,rb2.w),
                           pack_bf16x2(rb3.x,rb3.y), pack_bf16x2(rb3.z,rb3.w));
        __syncthreads();
        if (kt + TK < H_DIM) {
            int kq = (kt + TK) >> 2;
            ra0 = gA[kq]; ra1 = gA[kq+1]; ra2 = gA[kq+2]; ra3 = gA[kq+3];
            rb0 = gB[kq]; rb1 = gB[kq+1]; rb2 = gB[kq+2]; rb3 = gB[kq+3];
        }
        bf16x8 af[4], bfr[4];
        #pragma unroll
        for (int i = 0; i < 4; i++) {
            af[i]  = *(const bf16x8*)(sA + (wm*64 + i*16 + cl) * TK + q*8);
            bfr[i] = *(const bf16x8*)(sB + (wn*64 + i*16 + cl) * TK + q*8);
        }
        #pragma unroll
        for (int i = 0; i < 4; i++)
            #pragma unroll
            for (int j = 0; j < 4; j++)
                acc[i][j] = __builtin_amdgcn_mfma_f32_16x16x32_bf16(af[i], bfr[j], acc[i][j], 0, 0, 0);
        __syncthreads();
    }

    #pragma unroll
    for (int ti = 0; ti < 4; ti++) {
        #pragma unroll
        for (int r = 0; r < 4; r++) {
            float vals[4];
            #pragma unroll
            for (int j = 0; j < 4; j++) vals[j] = acc[ti][j][r];
            float m = vals[0]; int cj = 0;
            #pragma unroll
            for (int j = 1; j < 4; j++) if (vals[j] > m) { m = vals[j]; cj = j; }
            float s = 0.f;
            #pragma unroll
            for (int j = 0; j < 4; j++) s += __expf(vals[j] - m);
            int cidx = wn*64 + cj*16 + cl;
            #pragma unroll
            for (int off = 1; off < 16; off <<= 1) {
                float m2 = __shfl_xor(m, off);
                float s2 = __shfl_xor(s, off);
                int   c2 = __shfl_xor(cidx, off);
                float nm = fmaxf(m, m2);
                s = s * __expf(m - nm) + s2 * __expf(m2 - nm);
                if (m2 > m || (m2 == m && c2 < cidx)) cidx = c2;
                m = nm;
            }
            int rloc = wm*64 + ti*16 + q*4 + r;
            if (cl == 0) { redM[rloc*2+wn] = m; redS[rloc*2+wn] = s; redC[rloc*2+wn] = cidx; }
        }
    }
    __syncthreads();
    if (tid < TM) {
        float ma = redM[tid*2+0], mb = redM[tid*2+1];
        float sa = redS[tid*2+0], sb = redS[tid*2+1];
        int   ca = redC[tid*2+0], cb = redC[tid*2+1];
        float nm = fmaxf(ma, mb);
        float s  = sa * __expf(ma - nm) + sb * __expf(mb - nm);
        int   cc = (mb > ma || (mb == ma && cb < ca)) ? cb : ca;
        part[(size_t)(m0 + tid) * NBLK + nb] = make_float4(nm, s, __int_as_float(n0 + cc), 0.f);
    }

    if (token != nullptr) {
        if (tid < TM) tokloc[tid] = token[m0 + tid] - n0;
        __syncthreads();
        #pragma unroll
        for (int ti = 0; ti < 4; ti++) {
            #pragma unroll
            for (int r = 0; r < 4; r++) {
                int rloc = wm*64 + ti*16 + q*4 + r;
                int tl = tokloc[rloc];
                if (tl >= 0 && tl < TN && ((tl >> 6) & 1) == wn && (tl & 15) == cl) {
                    int tjm = (tl >> 4) & 3;
                    float v = acc[ti][0][r];
                    if (tjm == 1) v = acc[ti][1][r];
                    if (tjm == 2) v = acc[ti][2][r];
                    if (tjm == 3) v = acc[ti][3][r];
                    gather_out[m0 + rloc] = v;
                }
            }
        }
    }
}

// ---------------- reductions ----------------

__global__ __launch_bounds__(256) void reduce_policy_kernel(
    const float4* __restrict__ part, int* __restrict__ token, float* __restrict__ tok_logp)
{
    int row = blockIdx.x, t = threadIdx.x;
    float m = -3.0e38f, s = 0.f; int cc = 0x7fffffff;
    if (t < NBLK) { float4 p = part[(size_t)row * NBLK + t]; m = p.x; s = p.y; cc = __float_as_int(p.z); }
    for (int off = 1; off < 64; off <<= 1) {
        float m2 = __shfl_xor(m, off);
        float s2 = __shfl_xor(s, off);
        int   c2 = __shfl_xor(cc, off);
        float nm = fmaxf(m, m2);
        s = s * __expf(m - nm) + s2 * __expf(m2 - nm);
        if (m2 > m || (m2 == m && c2 < cc)) cc = c2;
        m = nm;
    }
    __shared__ float smM[4], smS[4]; __shared__ int smC[4];
    if ((t & 63) == 0) { smM[t>>6] = m; smS[t>>6] = s; smC[t>>6] = cc; }
    __syncthreads();
    if (t == 0) {
        m = smM[0]; s = smS[0]; cc = smC[0];
        for (int i = 1; i < 4; i++) {
            float m2 = smM[i], s2 = smS[i]; int c2 = smC[i];
            float nm = fmaxf(m, m2);
            s = s * __expf(m - nm) + s2 * __expf(m2 - nm);
            if (m2 > m || (m2 == m && c2 < cc)) cc = c2;
            m = nm;
        }
        token[row] = cc;
        tok_logp[row] = -__logf(s);    // token is argmax -> logit[token] == global max
    }
}

// gathered[row] = dot(ref_input[row], ref_weight[token[row]]) in exact fp32.
__global__ __launch_bounds__(256) void dot_gather_kernel(
    const float* __restrict__ rx, const float* __restrict__ rw,
    const int* __restrict__ token, float* __restrict__ out)
{
    int row = blockIdx.x, t = threadIdx.x;
    const float4* a = (const float4*)(rx + (size_t)row * H_DIM);
    const float4* b = (const float4*)(rw + (size_t)token[row] * H_DIM);
    float4 a0 = a[t*2], a1 = a[t*2+1], b0 = b[t*2], b1 = b[t*2+1];
    float s = a0.x*b0.x + a0.y*b0.y + a0.z*b0.z + a0.w*b0.w
            + a1.x*b1.x + a1.y*b1.y + a1.z*b1.z + a1.w*b1.w;
    for (int off = 1; off < 64; off <<= 1) s += __shfl_xor(s, off);
    __shared__ float ss[4];
    if ((t & 63) == 0) ss[t >> 6] = s;
    __syncthreads();
    if (t == 0) out[row] = ss[0] + ss[1] + ss[2] + ss[3];
}

__global__ __launch_bounds__(256) void reduce_ref_kernel(
    const float4* __restrict__ part, const float* __restrict__ tok_logp,
    const float* __restrict__ gathered, float* __restrict__ klrow)
{
    int row = blockIdx.x, t = threadIdx.x;
    float m = -3.0e38f, s = 0.f;
    if (t < NBLK) { float4 p = part[(size_t)row * NBLK + t]; m = p.x; s = p.y; }
    for (int off = 1; off < 64; off <<= 1) {
        float m2 = __shfl_xor(m, off), s2 = __shfl_xor(s, off);
        merge_ms(m, s, m2, s2);
    }
    __shared__ float smM[4], smS[4];
    if ((t & 63) == 0) { smM[t>>6] = m; smS[t>>6] = s; }
    __syncthreads();
    if (t == 0) {
        m = smM[0]; s = smS[0];
        for (int i = 1; i < 4; i++) merge_ms(m, s, smM[i], smS[i]);
        float lse = m + __logf(s);
        float d = (gathered[row] - lse) - tok_logp[row];   // ref_tok_logp - tok_logp
        klrow[row] = __expf(d) - d - 1.0f;
    }
}

__global__ __launch_bounds__(256) void final_kernel(
    const int* __restrict__ amask, const float* __restrict__ rewards,
    const float* __restrict__ klrow, float* __restrict__ out)
{
    int t = threadIdx.x;
    int b = t >> 5;
    int g = b >> 2;
    float r0 = rewards[g*4+0], r1 = rewards[g*4+1], r2 = rewards[g*4+2], r3 = rewards[g*4+3];
    float mean = 0.25f * (r0 + r1 + r2 + r3);
    float var = ((r0-mean)*(r0-mean) + (r1-mean)*(r1-mean) +
                 (r2-mean)*(r2-mean) + (r3-mean)*(r3-mean)) * (1.0f/3.0f);  // ddof=1
    float adv = (rewards[b] - mean) / (sqrtf(var) + EPSR);

    float ln = 0.f, ms = 0.f, kb = 0.f, mb = 0.f;
    for (int i = 0; i < 8; i++) {
        int row = t*8 + i;
        float mk = (float)amask[row];
        float kl = klrow[row];
        ln += (adv - BETA * kl) * mk;
        ms += mk;
        kb += kl * mk;
        mb += mk;
    }
    __shared__ float sLN[256], sMS[256], sKB[256], sMB[256], sKLb[8];
    sLN[t] = ln; sMS[t] = ms; sKB[t] = kb; sMB[t] = mb;
    __syncthreads();
    if (t < 8) {
        float skb = 0.f, smb = 0.f;
        for (int i = 0; i < 32; i++) { skb += sKB[t*32+i]; smb += sMB[t*32+i]; }
        sKLb[t] = skb / smb;
    }
    __syncthreads();
    if (t == 0) {
        float lnt = 0.f, mst = 0.f;
        for (int i = 0; i < 256; i++) { lnt += sLN[i]; mst += sMS[i]; }
        float mkl = 0.f;
        for (int i = 0; i < 8; i++) mkl += sKLb[i];
        out[0] = -lnt / mst;
        out[1] = mkl * 0.125f;
    }
}

// ---------------- launch ----------------

extern "C" void kernel_launch(void* const* d_in, const int* in_sizes, int n_in,
                              void* d_out, int out_size, void* d_ws, size_t ws_size,
                              hipStream_t stream)
{
    const float* x       = (const float*)d_in[0];
    const float* w       = (const float*)d_in[1];
    const int*   amask   = (const int*)  d_in[2];
    const float* rewards = (const float*)d_in[3];
    const float* rx      = (const float*)d_in[4];
    const float* rw      = (const float*)d_in[5];
    float* out = (float*)d_out;
    char* ws = (char*)d_ws;

    const size_t W_P  = (size_t)V_DIM * H_DIM * 2;   // 131,072,000 bf16 bytes
    const size_t A_P  = (size_t)BT * H_DIM * 2;      //   8,388,608
    const size_t PART = (size_t)BT * NBLK * 16;      //   8,192,000
    const size_t NEED = 2*W_P + 2*A_P + 2*PART + 4*8192;

    if (ws_size >= NEED) {
        // ---- fast path: pack to bf16 slabs, m97-style GEMM, exact-dot gather ----
        ushort* Wp   = (ushort*)(ws);
        ushort* RWp  = (ushort*)(ws + W_P);
        ushort* Ap   = (ushort*)(ws + 2*W_P);
        ushort* Rp   = (ushort*)(ws + 2*W_P + A_P);
        float4* part  = (float4*)(ws + 2*W_P + 2*A_P);
        float4* part2 = (float4*)(ws + 2*W_P + 2*A_P + PART);
        char*   tail  =          ws + 2*W_P + 2*A_P + 2*PART;
        int*   token    = (int*)  (tail);
        float* tok_logp = (float*)(tail + 8192);
        float* gathered = (float*)(tail + 16384);
        float* klrow    = (float*)(tail + 24576);

        pack_kernel<<<dim3(BT/128,  NKT), 256, 0, stream>>>(x,  (uint4*)Ap);
        pack_kernel<<<dim3(V_DIM/128, NKT), 256, 0, stream>>>(w,  (uint4*)Wp);
        pack_kernel<<<dim3(BT/128,  NKT), 256, 0, stream>>>(rx, (uint4*)Rp);
        pack_kernel<<<dim3(V_DIM/128, NKT), 256, 0, stream>>>(rw, (uint4*)RWp);

        gemm_lse_fast<<<dim3(BT/TM, NBLK, 2), 256, 0, stream>>>(Ap, Wp, Rp, RWp, part, part2);

        reduce_policy_kernel<<<BT, 256, 0, stream>>>(part, token, tok_logp);
        dot_gather_kernel<<<BT, 256, 0, stream>>>(rx, rw, token, gathered);
        reduce_ref_kernel<<<BT, 256, 0, stream>>>(part2, tok_logp, gathered, klrow);
        final_kernel<<<1, 256, 0, stream>>>(amask, rewards, klrow, out);
    } else {
        // ---- fallback: round-1 path (ws too small for packed weights) ----
        float4* part     = (float4*)ws;
        int*    token    = (int*)  (ws + PART);
        float*  tok_logp = (float*)(ws + PART + 8192);
        float*  gathered = (float*)(ws + PART + 16384);
        float*  klrow    = (float*)(ws + PART + 24576);

        dim3 g(BT / TM, NBLK), blk(256);
        gemm_lse_fallback<<<g, blk, 0, stream>>>(x, w, part, nullptr, nullptr);
        reduce_policy_kernel<<<BT, 256, 0, stream>>>(part, token, tok_logp);
        gemm_lse_fallback<<<g, blk, 0, stream>>>(rx, rw, part, token, gathered);
        reduce_ref_kernel<<<BT, 256, 0, stream>>>(part, tok_logp, gathered, klrow);
        final_kernel<<<1, 256, 0, stream>>>(amask, rewards, klrow, out);
    }
}